// Round 5
// baseline (673.963 us; speedup 1.0000x reference)
//
#include <hip/hip_runtime.h>

#define C 128
#define NB 512  // mega-kernel grid. Co-residency guaranteed: LDS 53.25KB -> 3 blocks/CU
                // capacity (160KB), we place 2/CU; VGPR capped at 128 via launch_bounds.

typedef __attribute__((ext_vector_type(8))) short short8;
typedef __attribute__((ext_vector_type(16))) float floatx16;

__device__ __forceinline__ unsigned short f2b(float f) {
    union { float f; unsigned u; } v; v.f = f;
    unsigned u = v.u + 0x7fffu + ((v.u >> 16) & 1u);  // RNE
    return (unsigned short)(u >> 16);
}
__device__ __forceinline__ void acc_pair(unsigned u, float& lo, float& hi) {
    union { unsigned u; float f; } a, b;
    a.u = u << 16;
    b.u = u & 0xffff0000u;
    lo += a.f;
    hi += b.f;
}

// ---- one-shot grid barrier: counter idx pre-zeroed by host memset, used exactly once ----
// Release fence before arrive flushes this block's writes to the coherent point (LLC);
// acquire fence after observe invalidates this CU's L1 / XCD's L2 so subsequent plain
// loads see other XCDs' writes. Counters 256B apart to avoid false sharing.
__device__ __forceinline__ void gbar(int* bar, int idx) {
    __syncthreads();
    if (threadIdx.x == 0) {
        int* c = bar + idx * 64;
        __threadfence();
        __hip_atomic_fetch_add(c, 1, __ATOMIC_RELEASE, __HIP_MEMORY_SCOPE_AGENT);
        while (__hip_atomic_load(c, __ATOMIC_ACQUIRE, __HIP_MEMORY_SCOPE_AGENT) < NB)
            __builtin_amdgcn_s_sleep(8);
        __threadfence();
    }
    __syncthreads();
}

// ------- mean aggregation phase: quarter-wave per node, 8-deep row ILP, block-stride -------
__device__ __forceinline__ void agg_phase(const unsigned short* __restrict__ xb,
                                          const int* __restrict__ row_start,
                                          const int* __restrict__ esrc,
                                          unsigned short* __restrict__ agg, int m,
                                          const int* __restrict__ nodelist) {
    int tid = threadIdx.x;
    int lane = tid & 63;
    int q = lane >> 4, l16 = lane & 15, qb = lane & 48;
    int wid = blockIdx.x * 4 + (tid >> 6);
    size_t choff = (size_t)l16 * 8;

    for (int pos = wid * 4 + q; pos < m; pos += NB * 16) {
        int node = nodelist ? nodelist[pos] : pos;
        int beg = row_start[node];
        int end = row_start[node + 1];
        float a0 = 0.f, a1 = 0.f, a2 = 0.f, a3 = 0.f, a4 = 0.f, a5 = 0.f, a6 = 0.f, a7 = 0.f;
        for (int base = beg; base < end; base += 16) {
            int cnt = min(end - base, 16);
            int e_val = (base + l16 < end) ? esrc[base + l16] : 0;
            int j = 0;
            for (; j + 8 <= cnt; j += 8) {
                int s0 = __shfl(e_val, qb | j, 64);
                int s1 = __shfl(e_val, qb | (j + 1), 64);
                int s2 = __shfl(e_val, qb | (j + 2), 64);
                int s3 = __shfl(e_val, qb | (j + 3), 64);
                int s4 = __shfl(e_val, qb | (j + 4), 64);
                int s5 = __shfl(e_val, qb | (j + 5), 64);
                int s6 = __shfl(e_val, qb | (j + 6), 64);
                int s7 = __shfl(e_val, qb | (j + 7), 64);
                uint4 v0 = *(const uint4*)(xb + (size_t)s0 * C + choff);
                uint4 v1 = *(const uint4*)(xb + (size_t)s1 * C + choff);
                uint4 v2 = *(const uint4*)(xb + (size_t)s2 * C + choff);
                uint4 v3 = *(const uint4*)(xb + (size_t)s3 * C + choff);
                uint4 v4 = *(const uint4*)(xb + (size_t)s4 * C + choff);
                uint4 v5 = *(const uint4*)(xb + (size_t)s5 * C + choff);
                uint4 v6 = *(const uint4*)(xb + (size_t)s6 * C + choff);
                uint4 v7 = *(const uint4*)(xb + (size_t)s7 * C + choff);
                acc_pair(v0.x, a0, a1); acc_pair(v0.y, a2, a3); acc_pair(v0.z, a4, a5); acc_pair(v0.w, a6, a7);
                acc_pair(v1.x, a0, a1); acc_pair(v1.y, a2, a3); acc_pair(v1.z, a4, a5); acc_pair(v1.w, a6, a7);
                acc_pair(v2.x, a0, a1); acc_pair(v2.y, a2, a3); acc_pair(v2.z, a4, a5); acc_pair(v2.w, a6, a7);
                acc_pair(v3.x, a0, a1); acc_pair(v3.y, a2, a3); acc_pair(v3.z, a4, a5); acc_pair(v3.w, a6, a7);
                acc_pair(v4.x, a0, a1); acc_pair(v4.y, a2, a3); acc_pair(v4.z, a4, a5); acc_pair(v4.w, a6, a7);
                acc_pair(v5.x, a0, a1); acc_pair(v5.y, a2, a3); acc_pair(v5.z, a4, a5); acc_pair(v5.w, a6, a7);
                acc_pair(v6.x, a0, a1); acc_pair(v6.y, a2, a3); acc_pair(v6.z, a4, a5); acc_pair(v6.w, a6, a7);
                acc_pair(v7.x, a0, a1); acc_pair(v7.y, a2, a3); acc_pair(v7.z, a4, a5); acc_pair(v7.w, a6, a7);
            }
            for (; j + 4 <= cnt; j += 4) {
                int s0 = __shfl(e_val, qb | j, 64);
                int s1 = __shfl(e_val, qb | (j + 1), 64);
                int s2 = __shfl(e_val, qb | (j + 2), 64);
                int s3 = __shfl(e_val, qb | (j + 3), 64);
                uint4 v0 = *(const uint4*)(xb + (size_t)s0 * C + choff);
                uint4 v1 = *(const uint4*)(xb + (size_t)s1 * C + choff);
                uint4 v2 = *(const uint4*)(xb + (size_t)s2 * C + choff);
                uint4 v3 = *(const uint4*)(xb + (size_t)s3 * C + choff);
                acc_pair(v0.x, a0, a1); acc_pair(v0.y, a2, a3); acc_pair(v0.z, a4, a5); acc_pair(v0.w, a6, a7);
                acc_pair(v1.x, a0, a1); acc_pair(v1.y, a2, a3); acc_pair(v1.z, a4, a5); acc_pair(v1.w, a6, a7);
                acc_pair(v2.x, a0, a1); acc_pair(v2.y, a2, a3); acc_pair(v2.z, a4, a5); acc_pair(v2.w, a6, a7);
                acc_pair(v3.x, a0, a1); acc_pair(v3.y, a2, a3); acc_pair(v3.z, a4, a5); acc_pair(v3.w, a6, a7);
            }
            for (; j < cnt; ++j) {
                int s0 = __shfl(e_val, qb | j, 64);
                uint4 v0 = *(const uint4*)(xb + (size_t)s0 * C + choff);
                acc_pair(v0.x, a0, a1); acc_pair(v0.y, a2, a3); acc_pair(v0.z, a4, a5); acc_pair(v0.w, a6, a7);
            }
        }
        float sc = 1.0f / fmaxf((float)(end - beg), 1.0f);
        uint4 o;
        o.x = ((unsigned)f2b(a1 * sc) << 16) | (unsigned)f2b(a0 * sc);
        o.y = ((unsigned)f2b(a3 * sc) << 16) | (unsigned)f2b(a2 * sc);
        o.z = ((unsigned)f2b(a5 * sc) << 16) | (unsigned)f2b(a4 * sc);
        o.w = ((unsigned)f2b(a7 * sc) << 16) | (unsigned)f2b(a6 * sc);
        *(uint4*)(agg + (size_t)pos * C + choff) = o;
    }
}

// ---- one 64x128 GEMM tile (h = agg@Wn^T + x@Wr^T + b) + LN + ReLU (+head if Whb) ----
__device__ __forceinline__ void gemm_tile(
    unsigned short (*Xs)[136], unsigned short (*Ws)[136], float (*Ls)[2], float (*Lss)[2],
    const unsigned short* __restrict__ Aagg, const unsigned short* __restrict__ Xin,
    const unsigned short* __restrict__ Wn, const unsigned short* __restrict__ Wr,
    const float* __restrict__ bconv, const float* __restrict__ gamma,
    const float* __restrict__ beta, unsigned short* __restrict__ Xout,
    int row0, int m, const int* __restrict__ nodelist,
    const unsigned short* __restrict__ Whb, const float* __restrict__ bh,
    float* __restrict__ out) {
    int tid = threadIdx.x;
    int wave = tid >> 6, lane = tid & 63;
    int rh = wave & 1, ch = wave >> 1;
    int l31 = lane & 31, half = lane >> 5;

    floatx16 acc0, acc1;
#pragma unroll
    for (int i = 0; i < 16; ++i) { acc0[i] = 0.f; acc1[i] = 0.f; }

#pragma unroll
    for (int phase = 0; phase < 2; ++phase) {
        const unsigned short* Ap = phase ? Xin : Aagg;
        const unsigned short* Wp = phase ? Wr : Wn;
        __syncthreads();
#pragma unroll
        for (int i = 0; i < 4; ++i) {
            int cidx = tid + 256 * i;
            int r = cidx >> 4, koff = (cidx & 15) * 8;
            uint4 v = make_uint4(0u, 0u, 0u, 0u);
            int rg = row0 + r;
            if (rg < m) {
                int rowid = (phase && nodelist) ? nodelist[rg] : rg;
                v = *(const uint4*)(Ap + (size_t)rowid * C + koff);
            }
            *(uint4*)&Xs[r][koff] = v;
        }
#pragma unroll
        for (int i = 0; i < 8; ++i) {
            int cidx = tid + 256 * i;
            int r = cidx >> 4, koff = (cidx & 15) * 8;
            uint4 v = *(const uint4*)(Wp + (size_t)r * C + koff);
            *(uint4*)&Ws[r][koff] = v;
        }
        __syncthreads();
#pragma unroll
        for (int kc = 0; kc < C; kc += 16) {
            int ko = kc + half * 8;
            short8 a = *(const short8*)&Xs[rh * 32 + l31][ko];
            short8 b0 = *(const short8*)&Ws[ch * 64 + l31][ko];
            short8 b1 = *(const short8*)&Ws[ch * 64 + 32 + l31][ko];
            acc0 = __builtin_amdgcn_mfma_f32_32x32x16_bf16(a, b0, acc0, 0, 0, 0);
            acc1 = __builtin_amdgcn_mfma_f32_32x32x16_bf16(a, b1, acc1, 0, 0, 0);
        }
    }

    int col0 = ch * 64 + l31;
    int col1 = col0 + 32;
    float bc0 = bconv[col0], bc1 = bconv[col1];
#pragma unroll
    for (int r = 0; r < 16; ++r) {
        float h0 = acc0[r] + bc0;
        float h1 = acc1[r] + bc1;
        float s = h0 + h1, ss = h0 * h0 + h1 * h1;
#pragma unroll
        for (int mk = 1; mk < 32; mk <<= 1) {
            s += __shfl_xor(s, mk, 64);
            ss += __shfl_xor(ss, mk, 64);
        }
        if (l31 == 0) {
            int row_l = rh * 32 + (r & 3) + 8 * (r >> 2) + 4 * half;
            Ls[row_l][ch] = s;
            Lss[row_l][ch] = ss;
        }
    }
    __syncthreads();  // all MFMA done; Ls/Lss visible; Xs/Ws safe to overwrite

    if (Whb) {
#pragma unroll
        for (int i = 0; i < 4; ++i) {
            int cidx = tid + 256 * i;
            int r = cidx >> 4, koff = (cidx & 15) * 8;
            uint4 v = *(const uint4*)(Whb + (size_t)r * C + koff);
            *(uint4*)&Ws[r][koff] = v;
        }
    }

    float g0 = gamma[col0], g1 = gamma[col1];
    float be0 = beta[col0], be1 = beta[col1];
#pragma unroll
    for (int r = 0; r < 16; ++r) {
        int row_l = rh * 32 + (r & 3) + 8 * (r >> 2) + 4 * half;
        float s = Ls[row_l][0] + Ls[row_l][1];
        float ss = Lss[row_l][0] + Lss[row_l][1];
        float mu = s * (1.0f / 128.0f);
        float var = ss * (1.0f / 128.0f) - mu * mu;
        float rs = rsqrtf(var + 1e-5f);
        float h0 = acc0[r] + bc0;
        float h1 = acc1[r] + bc1;
        float o0 = fmaxf((h0 - mu) * rs * g0 + be0, 0.f);
        float o1 = fmaxf((h1 - mu) * rs * g1 + be1, 0.f);
        Xs[row_l][col0] = f2b(o0);
        Xs[row_l][col1] = f2b(o1);
    }
    __syncthreads();  // post-LN tile complete in Xs (and Wh in Ws if final)

    if (Whb) {
        floatx16 hc;
#pragma unroll
        for (int i = 0; i < 16; ++i) hc[i] = 0.f;
        int m0 = rh * 32, n0 = ch * 32;
#pragma unroll
        for (int kc = 0; kc < C; kc += 16) {
            int ko = kc + half * 8;
            short8 a = *(const short8*)&Xs[m0 + l31][ko];
            short8 b = *(const short8*)&Ws[n0 + l31][ko];
            hc = __builtin_amdgcn_mfma_f32_32x32x16_bf16(a, b, hc, 0, 0, 0);
        }
        int oc = n0 + l31;
        float bhv = bh[oc];
#pragma unroll
        for (int r = 0; r < 16; ++r) {
            int row_l = m0 + (r & 3) + 8 * (r >> 2) + 4 * half;
            int rg = row0 + row_l;
            if (rg < m) out[(size_t)rg * 64 + oc] = hc[r] + bhv;
        }
    } else {
#pragma unroll
        for (int i = 0; i < 4; ++i) {
            int cidx = tid + 256 * i;
            int r = cidx >> 4, koff = (cidx & 15) * 8;
            int rg = row0 + r;
            if (rg < m) {
                int orow = nodelist ? nodelist[rg] : rg;
                *(uint4*)(Xout + (size_t)orow * C + koff) = *(const uint4*)&Xs[r][koff];
            }
        }
    }
}

// ================= PERSISTENT MEGA-KERNEL: whole model in one dispatch =================
// Phases separated by one-shot grid barriers (counters pre-zeroed by host memset).
// No thread returns before the last barrier it participates in.
__launch_bounds__(256, 2)
__global__ void mega_kernel(const float* __restrict__ x,
                            const int* __restrict__ src, const int* __restrict__ dst,
                            const float* __restrict__ Wn, const float* __restrict__ Wr,
                            const float* __restrict__ bconv, const float* __restrict__ gamma,
                            const float* __restrict__ beta,
                            const float* __restrict__ Wh, const float* __restrict__ bh,
                            float* __restrict__ out,
                            int N, int E, int L, int num_seed, int nchunks, int useFrontier,
                            int n4x, int n4w, int n4h,
                            int* __restrict__ bar, int* __restrict__ deg, int* __restrict__ needed,
                            int* __restrict__ row_start, int* __restrict__ cursor,
                            int* __restrict__ nodelist, int* __restrict__ Mptr,
                            int* __restrict__ bsumD, int* __restrict__ bsumN,
                            int* __restrict__ esrc,
                            unsigned short* __restrict__ xb, unsigned short* __restrict__ aggb,
                            unsigned short* __restrict__ xA, unsigned short* __restrict__ xB,
                            unsigned short* __restrict__ Wnb, unsigned short* __restrict__ Wrb,
                            unsigned short* __restrict__ Whb) {
    __shared__ unsigned short Xs[64][136];
    __shared__ unsigned short Ws[128][136];
    __shared__ float Ls[64][2];
    __shared__ float Lss[64][2];

    int t = threadIdx.x;
    int g = blockIdx.x * 256 + t;
    int bi = 0;  // barrier index (uniform across blocks)

    // ---------- P0: casts + frontier mark + degree histogram (deg/needed pre-zeroed) ----------
    int n4tot = n4x + 2 * n4w + n4h;
    for (int i = g; i < n4tot; i += NB * 256) {
        const float* in;
        unsigned short* outp;
        int idx;
        if (i < n4x) { in = x; outp = xb; idx = i; }
        else if (i < n4x + n4w) { in = Wn; outp = Wnb; idx = i - n4x; }
        else if (i < n4x + 2 * n4w) { in = Wr; outp = Wrb; idx = i - n4x - n4w; }
        else { in = Wh; outp = Whb; idx = i - n4x - 2 * n4w; }
        float4 v = ((const float4*)in)[idx];
        ushort4 o;
        o.x = f2b(v.x); o.y = f2b(v.y); o.z = f2b(v.z); o.w = f2b(v.w);
        ((ushort4*)outp)[idx] = o;
    }
    for (int s = g; s < num_seed; s += NB * 256) needed[s] = 1;
    for (int e = g; e < E; e += NB * 256) {
        int d = dst[e];
        atomicAdd(&deg[d], 1);
        if (useFrontier && d < num_seed) needed[src[e]] = 1;
    }
    gbar(bar, bi++);

    // ---------- P1: scan-a (per-256-chunk sums of deg and needed) ----------
    int* smD = (int*)&Xs[0][0];
    int* smN = smD + 256;
    int* osmD = smD + 512;
    int* osmN = smD + 768;
    for (int cc = blockIdx.x; cc < nchunks; cc += NB) {
        int i = cc * 256 + t;
        smD[t] = (i < N) ? deg[i] : 0;
        smN[t] = (i < N) ? needed[i] : 0;
        __syncthreads();
#pragma unroll
        for (int off = 128; off > 0; off >>= 1) {
            if (t < off) { smD[t] += smD[t + off]; smN[t] += smN[t + off]; }
            __syncthreads();
        }
        if (t == 0) { bsumD[cc] = smD[0]; bsumN[cc] = smN[0]; }
        __syncthreads();
    }
    gbar(bar, bi++);

    // ---------- P2: scan-b (offsets + chunk scan + row_start/cursor/nodelist/Mptr) ----------
    for (int cc = blockIdx.x; cc < nchunks; cc += NB) {
        int sD = 0, sN = 0;
        for (int i = t; i < cc; i += 256) { sD += bsumD[i]; sN += bsumN[i]; }
        osmD[t] = sD; osmN[t] = sN;
        __syncthreads();
#pragma unroll
        for (int off = 128; off > 0; off >>= 1) {
            if (t < off) { osmD[t] += osmD[t + off]; osmN[t] += osmN[t + off]; }
            __syncthreads();
        }
        int boffD = osmD[0], boffN = osmN[0];
        int i = cc * 256 + t;
        int d = (i < N) ? deg[i] : 0;
        int nd = (i < N) ? needed[i] : 0;
        smD[t] = d; smN[t] = nd;
        __syncthreads();
        for (int off = 1; off < 256; off <<= 1) {
            int vD = (t >= off) ? smD[t - off] : 0;
            int vN = (t >= off) ? smN[t - off] : 0;
            __syncthreads();
            smD[t] += vD; smN[t] += vN;
            __syncthreads();
        }
        int exD = smD[t] - d + boffD;
        int exN = smN[t] - nd + boffN;
        if (i < N) {
            row_start[i] = exD;
            cursor[i] = exD;
            if (nd) nodelist[exN] = i;
            if (i == N - 1) { row_start[N] = exD + d; *Mptr = exN + nd; }
        }
        __syncthreads();
    }
    gbar(bar, bi++);

    // ---------- P3: bucket edges by dst (counting sort, frontier-filtered) ----------
    for (int e = g; e < E; e += NB * 256) {
        int d = dst[e];
        if (!useFrontier || needed[d]) {
            int p = atomicAdd(&cursor[d], 1);
            esrc[p] = src[e];
        }
    }
    gbar(bar, bi++);

    // ---------- layers ----------
    const unsigned short* cur = xb;
    unsigned short* bufs[2] = {xA, xB};
    for (int l = 0; l < L; ++l) {
        bool last = (l == L - 1);
        bool front = useFrontier && !last;  // L==2: layer 0 is the frontier layer
        int mrows = last ? num_seed
                         : (front ? __hip_atomic_load(Mptr, __ATOMIC_RELAXED,
                                                      __HIP_MEMORY_SCOPE_AGENT)
                                  : N);
        const int* list = front ? nodelist : nullptr;
        const unsigned short* Wn_l = Wnb + (size_t)l * C * C;
        const unsigned short* Wr_l = Wrb + (size_t)l * C * C;
        const float* bc_l = bconv + (size_t)l * C;
        const float* g_l = gamma + (size_t)l * C;
        const float* b_l = beta + (size_t)l * C;
        unsigned short* nxt = bufs[l & 1];

        agg_phase(cur, row_start, esrc, aggb, mrows, list);
        gbar(bar, bi++);

        for (int tile = blockIdx.x; tile * 64 < mrows; tile += NB)
            gemm_tile(Xs, Ws, Ls, Lss, aggb, cur, Wn_l, Wr_l, bc_l, g_l, b_l, nxt,
                      tile * 64, mrows, list, last ? Whb : (const unsigned short*)nullptr,
                      bh, out);
        if (!last) gbar(bar, bi++);
        cur = nxt;
    }
}

extern "C" void kernel_launch(void* const* d_in, const int* in_sizes, int n_in,
                              void* d_out, int out_size, void* d_ws, size_t ws_size,
                              hipStream_t stream) {
    const float* x = (const float*)d_in[0];
    const int* ei = (const int*)d_in[1];
    const float* Wn = (const float*)d_in[2];
    const float* Wr = (const float*)d_in[3];
    const float* bconv = (const float*)d_in[4];
    const float* gamma = (const float*)d_in[5];
    const float* beta = (const float*)d_in[6];
    const float* Wh = (const float*)d_in[7];
    const float* bh = (const float*)d_in[8];

    int N = in_sizes[0] / C;
    int E = in_sizes[1] / 2;
    int L = in_sizes[2] / (C * C);
    int num_seed = out_size / 64;
    int nchunks = (N + 255) / 256;

    char* ws = (char*)d_ws;
    size_t off = 0;
    auto alloc = [&](size_t bytes) {
        void* p = ws + off;
        off = (off + bytes + 255) & ~(size_t)255;
        return p;
    };
    // ---- zero region (one memset: barrier counters + deg + needed) ----
    int* bar = (int*)alloc((size_t)64 * 64 * 4);  // up to 64 one-shot barriers, 256B apart
    int* deg = (int*)alloc((size_t)N * 4);
    int* needed = (int*)alloc((size_t)N * 4);
    size_t zero_span = off;
    // ---- rest ----
    int* row_start = (int*)alloc((size_t)(N + 1) * 4);
    int* cursor = (int*)alloc((size_t)N * 4);
    int* nodelist = (int*)alloc((size_t)N * 4);
    int* Mptr = (int*)alloc(4);
    int* bsumD = (int*)alloc((size_t)nchunks * 4);
    int* bsumN = (int*)alloc((size_t)nchunks * 4);
    int* esrc = (int*)alloc((size_t)E * 4);
    unsigned short* xb = (unsigned short*)alloc((size_t)N * C * 2);
    unsigned short* aggb = (unsigned short*)alloc((size_t)N * C * 2);
    unsigned short* xA = (unsigned short*)alloc((size_t)N * C * 2);
    unsigned short* xB = (unsigned short*)alloc((size_t)N * C * 2);
    unsigned short* Wnb = (unsigned short*)alloc((size_t)L * C * C * 2);
    unsigned short* Wrb = (unsigned short*)alloc((size_t)L * C * C * 2);
    unsigned short* Whb = (unsigned short*)alloc((size_t)64 * C * 2);

    const int* srcIdx = ei;
    const int* dstIdx = ei + E;

    int n4x = N * C / 4;
    int n4w = L * C * C / 4;
    int n4h = 64 * C / 4;
    int useFrontier = (L == 2) ? 1 : 0;

    hipMemsetAsync(ws, 0, zero_span, stream);
    mega_kernel<<<NB, 256, 0, stream>>>(
        x, srcIdx, dstIdx, Wn, Wr, bconv, gamma, beta, Wh, bh, (float*)d_out,
        N, E, L, num_seed, nchunks, useFrontier, n4x, n4w, n4h,
        bar, deg, needed, row_start, cursor, nodelist, Mptr, bsumD, bsumN, esrc,
        xb, aggb, xA, xB, Wnb, Wrb, Whb);
}

// Round 8
// 415.718 us; speedup vs baseline: 1.6212x; 1.6212x over previous
//
#include <hip/hip_runtime.h>

#define C 128
#define NB 512  // mega-kernel grid. Co-residency proven by R5 run (occupancy 23.8% = 2/CU):
                // LDS 53.25KB (<=3/CU), VGPR ~104 (4/CU) -> 2 blocks/CU at grid 512.

typedef __attribute__((ext_vector_type(8))) short short8;
typedef __attribute__((ext_vector_type(16))) float floatx16;

__device__ __forceinline__ unsigned short f2b(float f) {
    union { float f; unsigned u; } v; v.f = f;
    unsigned u = v.u + 0x7fffu + ((v.u >> 16) & 1u);  // RNE
    return (unsigned short)(u >> 16);
}
__device__ __forceinline__ void acc_pair(unsigned u, float& lo, float& hi) {
    union { unsigned u; float f; } a, b;
    a.u = u << 16;
    b.u = u & 0xffff0000u;
    lo += a.f;
    hi += b.f;
}

// ---- one-shot grid barrier: counter idx pre-zeroed by host memset, used exactly once ----
// Protocol (R5/R6 post-mortems):
//   arrive: ONE release RMW (writes back this XCD's dirty L2 once; coherent-point add).
//   spin:   relaxed RMW fetch_add(0) -- RMWs execute at the coherent point, so remote
//           arrivals are ALWAYS observed (R6's relaxed LOAD spun on stale cache -> hang),
//           and relaxed ordering emits no per-iteration cache invalidate (R5's acquire
//           load spin stalled the chip at 131 GB/s for 648us).
//   exit:   ONE acquire fence (single invalidate so subsequent plain loads see remote data).
// s_sleep(8) (~512 cy) between polls caps LLC RMW traffic from 512 spinners.
// (R7: s_sleep arg must be a CONSTANT -- variable backoff does not compile.)
__device__ __forceinline__ void gbar(int* bar, int idx) {
    __syncthreads();
    if (threadIdx.x == 0) {
        int* c = bar + idx * 64;  // counters 256B apart
        __hip_atomic_fetch_add(c, 1, __ATOMIC_RELEASE, __HIP_MEMORY_SCOPE_AGENT);
        while (__hip_atomic_fetch_add(c, 0, __ATOMIC_RELAXED, __HIP_MEMORY_SCOPE_AGENT) < NB)
            __builtin_amdgcn_s_sleep(8);
        __builtin_amdgcn_fence(__ATOMIC_ACQUIRE, "agent");
    }
    __syncthreads();
}

// ------- mean aggregation phase: quarter-wave per node, 8-deep row ILP, block-stride -------
__device__ __forceinline__ void agg_phase(const unsigned short* __restrict__ xb,
                                          const int* __restrict__ row_start,
                                          const int* __restrict__ esrc,
                                          unsigned short* __restrict__ agg, int m,
                                          const int* __restrict__ nodelist) {
    int tid = threadIdx.x;
    int lane = tid & 63;
    int q = lane >> 4, l16 = lane & 15, qb = lane & 48;
    int wid = blockIdx.x * 4 + (tid >> 6);
    size_t choff = (size_t)l16 * 8;

    for (int pos = wid * 4 + q; pos < m; pos += NB * 16) {
        int node = nodelist ? nodelist[pos] : pos;
        int beg = row_start[node];
        int end = row_start[node + 1];
        float a0 = 0.f, a1 = 0.f, a2 = 0.f, a3 = 0.f, a4 = 0.f, a5 = 0.f, a6 = 0.f, a7 = 0.f;
        for (int base = beg; base < end; base += 16) {
            int cnt = min(end - base, 16);
            int e_val = (base + l16 < end) ? esrc[base + l16] : 0;
            int j = 0;
            for (; j + 8 <= cnt; j += 8) {
                int s0 = __shfl(e_val, qb | j, 64);
                int s1 = __shfl(e_val, qb | (j + 1), 64);
                int s2 = __shfl(e_val, qb | (j + 2), 64);
                int s3 = __shfl(e_val, qb | (j + 3), 64);
                int s4 = __shfl(e_val, qb | (j + 4), 64);
                int s5 = __shfl(e_val, qb | (j + 5), 64);
                int s6 = __shfl(e_val, qb | (j + 6), 64);
                int s7 = __shfl(e_val, qb | (j + 7), 64);
                uint4 v0 = *(const uint4*)(xb + (size_t)s0 * C + choff);
                uint4 v1 = *(const uint4*)(xb + (size_t)s1 * C + choff);
                uint4 v2 = *(const uint4*)(xb + (size_t)s2 * C + choff);
                uint4 v3 = *(const uint4*)(xb + (size_t)s3 * C + choff);
                uint4 v4 = *(const uint4*)(xb + (size_t)s4 * C + choff);
                uint4 v5 = *(const uint4*)(xb + (size_t)s5 * C + choff);
                uint4 v6 = *(const uint4*)(xb + (size_t)s6 * C + choff);
                uint4 v7 = *(const uint4*)(xb + (size_t)s7 * C + choff);
                acc_pair(v0.x, a0, a1); acc_pair(v0.y, a2, a3); acc_pair(v0.z, a4, a5); acc_pair(v0.w, a6, a7);
                acc_pair(v1.x, a0, a1); acc_pair(v1.y, a2, a3); acc_pair(v1.z, a4, a5); acc_pair(v1.w, a6, a7);
                acc_pair(v2.x, a0, a1); acc_pair(v2.y, a2, a3); acc_pair(v2.z, a4, a5); acc_pair(v2.w, a6, a7);
                acc_pair(v3.x, a0, a1); acc_pair(v3.y, a2, a3); acc_pair(v3.z, a4, a5); acc_pair(v3.w, a6, a7);
                acc_pair(v4.x, a0, a1); acc_pair(v4.y, a2, a3); acc_pair(v4.z, a4, a5); acc_pair(v4.w, a6, a7);
                acc_pair(v5.x, a0, a1); acc_pair(v5.y, a2, a3); acc_pair(v5.z, a4, a5); acc_pair(v5.w, a6, a7);
                acc_pair(v6.x, a0, a1); acc_pair(v6.y, a2, a3); acc_pair(v6.z, a4, a5); acc_pair(v6.w, a6, a7);
                acc_pair(v7.x, a0, a1); acc_pair(v7.y, a2, a3); acc_pair(v7.z, a4, a5); acc_pair(v7.w, a6, a7);
            }
            for (; j + 4 <= cnt; j += 4) {
                int s0 = __shfl(e_val, qb | j, 64);
                int s1 = __shfl(e_val, qb | (j + 1), 64);
                int s2 = __shfl(e_val, qb | (j + 2), 64);
                int s3 = __shfl(e_val, qb | (j + 3), 64);
                uint4 v0 = *(const uint4*)(xb + (size_t)s0 * C + choff);
                uint4 v1 = *(const uint4*)(xb + (size_t)s1 * C + choff);
                uint4 v2 = *(const uint4*)(xb + (size_t)s2 * C + choff);
                uint4 v3 = *(const uint4*)(xb + (size_t)s3 * C + choff);
                acc_pair(v0.x, a0, a1); acc_pair(v0.y, a2, a3); acc_pair(v0.z, a4, a5); acc_pair(v0.w, a6, a7);
                acc_pair(v1.x, a0, a1); acc_pair(v1.y, a2, a3); acc_pair(v1.z, a4, a5); acc_pair(v1.w, a6, a7);
                acc_pair(v2.x, a0, a1); acc_pair(v2.y, a2, a3); acc_pair(v2.z, a4, a5); acc_pair(v2.w, a6, a7);
                acc_pair(v3.x, a0, a1); acc_pair(v3.y, a2, a3); acc_pair(v3.z, a4, a5); acc_pair(v3.w, a6, a7);
            }
            for (; j < cnt; ++j) {
                int s0 = __shfl(e_val, qb | j, 64);
                uint4 v0 = *(const uint4*)(xb + (size_t)s0 * C + choff);
                acc_pair(v0.x, a0, a1); acc_pair(v0.y, a2, a3); acc_pair(v0.z, a4, a5); acc_pair(v0.w, a6, a7);
            }
        }
        float sc = 1.0f / fmaxf((float)(end - beg), 1.0f);
        uint4 o;
        o.x = ((unsigned)f2b(a1 * sc) << 16) | (unsigned)f2b(a0 * sc);
        o.y = ((unsigned)f2b(a3 * sc) << 16) | (unsigned)f2b(a2 * sc);
        o.z = ((unsigned)f2b(a5 * sc) << 16) | (unsigned)f2b(a4 * sc);
        o.w = ((unsigned)f2b(a7 * sc) << 16) | (unsigned)f2b(a6 * sc);
        *(uint4*)(agg + (size_t)pos * C + choff) = o;
    }
}

// ---- one 64x128 GEMM tile (h = agg@Wn^T + x@Wr^T + b) + LN + ReLU (+head if Whb) ----
__device__ __forceinline__ void gemm_tile(
    unsigned short (*Xs)[136], unsigned short (*Ws)[136], float (*Ls)[2], float (*Lss)[2],
    const unsigned short* __restrict__ Aagg, const unsigned short* __restrict__ Xin,
    const unsigned short* __restrict__ Wn, const unsigned short* __restrict__ Wr,
    const float* __restrict__ bconv, const float* __restrict__ gamma,
    const float* __restrict__ beta, unsigned short* __restrict__ Xout,
    int row0, int m, const int* __restrict__ nodelist,
    const unsigned short* __restrict__ Whb, const float* __restrict__ bh,
    float* __restrict__ out) {
    int tid = threadIdx.x;
    int wave = tid >> 6, lane = tid & 63;
    int rh = wave & 1, ch = wave >> 1;
    int l31 = lane & 31, half = lane >> 5;

    floatx16 acc0, acc1;
#pragma unroll
    for (int i = 0; i < 16; ++i) { acc0[i] = 0.f; acc1[i] = 0.f; }

#pragma unroll
    for (int phase = 0; phase < 2; ++phase) {
        const unsigned short* Ap = phase ? Xin : Aagg;
        const unsigned short* Wp = phase ? Wr : Wn;
        __syncthreads();
#pragma unroll
        for (int i = 0; i < 4; ++i) {
            int cidx = tid + 256 * i;
            int r = cidx >> 4, koff = (cidx & 15) * 8;
            uint4 v = make_uint4(0u, 0u, 0u, 0u);
            int rg = row0 + r;
            if (rg < m) {
                int rowid = (phase && nodelist) ? nodelist[rg] : rg;
                v = *(const uint4*)(Ap + (size_t)rowid * C + koff);
            }
            *(uint4*)&Xs[r][koff] = v;
        }
#pragma unroll
        for (int i = 0; i < 8; ++i) {
            int cidx = tid + 256 * i;
            int r = cidx >> 4, koff = (cidx & 15) * 8;
            uint4 v = *(const uint4*)(Wp + (size_t)r * C + koff);
            *(uint4*)&Ws[r][koff] = v;
        }
        __syncthreads();
#pragma unroll
        for (int kc = 0; kc < C; kc += 16) {
            int ko = kc + half * 8;
            short8 a = *(const short8*)&Xs[rh * 32 + l31][ko];
            short8 b0 = *(const short8*)&Ws[ch * 64 + l31][ko];
            short8 b1 = *(const short8*)&Ws[ch * 64 + 32 + l31][ko];
            acc0 = __builtin_amdgcn_mfma_f32_32x32x16_bf16(a, b0, acc0, 0, 0, 0);
            acc1 = __builtin_amdgcn_mfma_f32_32x32x16_bf16(a, b1, acc1, 0, 0, 0);
        }
    }

    int col0 = ch * 64 + l31;
    int col1 = col0 + 32;
    float bc0 = bconv[col0], bc1 = bconv[col1];
#pragma unroll
    for (int r = 0; r < 16; ++r) {
        float h0 = acc0[r] + bc0;
        float h1 = acc1[r] + bc1;
        float s = h0 + h1, ss = h0 * h0 + h1 * h1;
#pragma unroll
        for (int mk = 1; mk < 32; mk <<= 1) {
            s += __shfl_xor(s, mk, 64);
            ss += __shfl_xor(ss, mk, 64);
        }
        if (l31 == 0) {
            int row_l = rh * 32 + (r & 3) + 8 * (r >> 2) + 4 * half;
            Ls[row_l][ch] = s;
            Lss[row_l][ch] = ss;
        }
    }
    __syncthreads();  // all MFMA done; Ls/Lss visible; Xs/Ws safe to overwrite

    if (Whb) {
#pragma unroll
        for (int i = 0; i < 4; ++i) {
            int cidx = tid + 256 * i;
            int r = cidx >> 4, koff = (cidx & 15) * 8;
            uint4 v = *(const uint4*)(Whb + (size_t)r * C + koff);
            *(uint4*)&Ws[r][koff] = v;
        }
    }

    float g0 = gamma[col0], g1 = gamma[col1];
    float be0 = beta[col0], be1 = beta[col1];
#pragma unroll
    for (int r = 0; r < 16; ++r) {
        int row_l = rh * 32 + (r & 3) + 8 * (r >> 2) + 4 * half;
        float s = Ls[row_l][0] + Ls[row_l][1];
        float ss = Lss[row_l][0] + Lss[row_l][1];
        float mu = s * (1.0f / 128.0f);
        float var = ss * (1.0f / 128.0f) - mu * mu;
        float rs = rsqrtf(var + 1e-5f);
        float h0 = acc0[r] + bc0;
        float h1 = acc1[r] + bc1;
        float o0 = fmaxf((h0 - mu) * rs * g0 + be0, 0.f);
        float o1 = fmaxf((h1 - mu) * rs * g1 + be1, 0.f);
        Xs[row_l][col0] = f2b(o0);
        Xs[row_l][col1] = f2b(o1);
    }
    __syncthreads();  // post-LN tile complete in Xs (and Wh in Ws if final)

    if (Whb) {
        floatx16 hc;
#pragma unroll
        for (int i = 0; i < 16; ++i) hc[i] = 0.f;
        int m0 = rh * 32, n0 = ch * 32;
#pragma unroll
        for (int kc = 0; kc < C; kc += 16) {
            int ko = kc + half * 8;
            short8 a = *(const short8*)&Xs[m0 + l31][ko];
            short8 b = *(const short8*)&Ws[n0 + l31][ko];
            hc = __builtin_amdgcn_mfma_f32_32x32x16_bf16(a, b, hc, 0, 0, 0);
        }
        int oc = n0 + l31;
        float bhv = bh[oc];
#pragma unroll
        for (int r = 0; r < 16; ++r) {
            int row_l = m0 + (r & 3) + 8 * (r >> 2) + 4 * half;
            int rg = row0 + row_l;
            if (rg < m) out[(size_t)rg * 64 + oc] = hc[r] + bhv;
        }
    } else {
#pragma unroll
        for (int i = 0; i < 4; ++i) {
            int cidx = tid + 256 * i;
            int r = cidx >> 4, koff = (cidx & 15) * 8;
            int rg = row0 + r;
            if (rg < m) {
                int orow = nodelist ? nodelist[rg] : rg;
                *(uint4*)(Xout + (size_t)orow * C + koff) = *(const uint4*)&Xs[r][koff];
            }
        }
    }
}

// ================= PERSISTENT MEGA-KERNEL: whole model in one dispatch =================
// Phases separated by one-shot grid barriers (counters pre-zeroed by host memset).
__launch_bounds__(256, 2)
__global__ void mega_kernel(const float* __restrict__ x,
                            const int* __restrict__ src, const int* __restrict__ dst,
                            const float* __restrict__ Wn, const float* __restrict__ Wr,
                            const float* __restrict__ bconv, const float* __restrict__ gamma,
                            const float* __restrict__ beta,
                            const float* __restrict__ Wh, const float* __restrict__ bh,
                            float* __restrict__ out,
                            int N, int E, int L, int num_seed, int nchunks, int useFrontier,
                            int n4x, int n4w, int n4h,
                            int* __restrict__ bar, int* __restrict__ deg, int* __restrict__ needed,
                            int* __restrict__ row_start, int* __restrict__ cursor,
                            int* __restrict__ nodelist, int* __restrict__ Mptr,
                            int* __restrict__ bsumD, int* __restrict__ bsumN,
                            int* __restrict__ esrc,
                            unsigned short* __restrict__ xb, unsigned short* __restrict__ aggb,
                            unsigned short* __restrict__ xA, unsigned short* __restrict__ xB,
                            unsigned short* __restrict__ Wnb, unsigned short* __restrict__ Wrb,
                            unsigned short* __restrict__ Whb) {
    __shared__ unsigned short Xs[64][136];
    __shared__ unsigned short Ws[128][136];
    __shared__ float Ls[64][2];
    __shared__ float Lss[64][2];

    int t = threadIdx.x;
    int g = blockIdx.x * 256 + t;
    int bi = 0;  // barrier index (uniform across blocks)

    // ---------- P0: casts + frontier mark + degree histogram (deg/needed pre-zeroed) ----------
    int n4tot = n4x + 2 * n4w + n4h;
    for (int i = g; i < n4tot; i += NB * 256) {
        const float* in;
        unsigned short* outp;
        int idx;
        if (i < n4x) { in = x; outp = xb; idx = i; }
        else if (i < n4x + n4w) { in = Wn; outp = Wnb; idx = i - n4x; }
        else if (i < n4x + 2 * n4w) { in = Wr; outp = Wrb; idx = i - n4x - n4w; }
        else { in = Wh; outp = Whb; idx = i - n4x - 2 * n4w; }
        float4 v = ((const float4*)in)[idx];
        ushort4 o;
        o.x = f2b(v.x); o.y = f2b(v.y); o.z = f2b(v.z); o.w = f2b(v.w);
        ((ushort4*)outp)[idx] = o;
    }
    for (int s = g; s < num_seed; s += NB * 256) needed[s] = 1;
    for (int e = g; e < E; e += NB * 256) {
        int d = dst[e];
        atomicAdd(&deg[d], 1);
        if (useFrontier && d < num_seed) needed[src[e]] = 1;
    }
    gbar(bar, bi++);

    // ---------- P1: scan-a (per-256-chunk sums of deg and needed) ----------
    int* smD = (int*)&Xs[0][0];
    int* smN = smD + 256;
    int* osmD = smD + 512;
    int* osmN = smD + 768;
    for (int cc = blockIdx.x; cc < nchunks; cc += NB) {
        int i = cc * 256 + t;
        smD[t] = (i < N) ? deg[i] : 0;
        smN[t] = (i < N) ? needed[i] : 0;
        __syncthreads();
#pragma unroll
        for (int off = 128; off > 0; off >>= 1) {
            if (t < off) { smD[t] += smD[t + off]; smN[t] += smN[t + off]; }
            __syncthreads();
        }
        if (t == 0) { bsumD[cc] = smD[0]; bsumN[cc] = smN[0]; }
        __syncthreads();
    }
    gbar(bar, bi++);

    // ---------- P2: scan-b (offsets + chunk scan + row_start/cursor/nodelist/Mptr) ----------
    for (int cc = blockIdx.x; cc < nchunks; cc += NB) {
        int sD = 0, sN = 0;
        for (int i = t; i < cc; i += 256) { sD += bsumD[i]; sN += bsumN[i]; }
        osmD[t] = sD; osmN[t] = sN;
        __syncthreads();
#pragma unroll
        for (int off = 128; off > 0; off >>= 1) {
            if (t < off) { osmD[t] += osmD[t + off]; osmN[t] += osmN[t + off]; }
            __syncthreads();
        }
        int boffD = osmD[0], boffN = osmN[0];
        int i = cc * 256 + t;
        int d = (i < N) ? deg[i] : 0;
        int nd = (i < N) ? needed[i] : 0;
        smD[t] = d; smN[t] = nd;
        __syncthreads();
        for (int off = 1; off < 256; off <<= 1) {
            int vD = (t >= off) ? smD[t - off] : 0;
            int vN = (t >= off) ? smN[t - off] : 0;
            __syncthreads();
            smD[t] += vD; smN[t] += vN;
            __syncthreads();
        }
        int exD = smD[t] - d + boffD;
        int exN = smN[t] - nd + boffN;
        if (i < N) {
            row_start[i] = exD;
            cursor[i] = exD;
            if (nd) nodelist[exN] = i;
            if (i == N - 1) { row_start[N] = exD + d; *Mptr = exN + nd; }
        }
        __syncthreads();
    }
    gbar(bar, bi++);

    // ---------- P3: bucket edges by dst (counting sort, frontier-filtered) ----------
    for (int e = g; e < E; e += NB * 256) {
        int d = dst[e];
        if (!useFrontier || needed[d]) {
            int p = atomicAdd(&cursor[d], 1);
            esrc[p] = src[e];
        }
    }
    gbar(bar, bi++);

    // ---------- layers ----------
    const unsigned short* cur = xb;
    unsigned short* bufs[2] = {xA, xB};
    for (int l = 0; l < L; ++l) {
        bool last = (l == L - 1);
        bool front = useFrontier && !last;  // L==2: layer 0 is the frontier layer
        int mrows = last ? num_seed
                         : (front ? *Mptr : N);
        const int* list = front ? nodelist : nullptr;
        const unsigned short* Wn_l = Wnb + (size_t)l * C * C;
        const unsigned short* Wr_l = Wrb + (size_t)l * C * C;
        const float* bc_l = bconv + (size_t)l * C;
        const float* g_l = gamma + (size_t)l * C;
        const float* b_l = beta + (size_t)l * C;
        unsigned short* nxt = bufs[l & 1];

        agg_phase(cur, row_start, esrc, aggb, mrows, list);
        gbar(bar, bi++);

        for (int tile = blockIdx.x; tile * 64 < mrows; tile += NB)
            gemm_tile(Xs, Ws, Ls, Lss, aggb, cur, Wn_l, Wr_l, bc_l, g_l, b_l, nxt,
                      tile * 64, mrows, list, last ? Whb : (const unsigned short*)nullptr,
                      bh, out);
        if (!last) gbar(bar, bi++);
        cur = nxt;
    }
}

extern "C" void kernel_launch(void* const* d_in, const int* in_sizes, int n_in,
                              void* d_out, int out_size, void* d_ws, size_t ws_size,
                              hipStream_t stream) {
    const float* x = (const float*)d_in[0];
    const int* ei = (const int*)d_in[1];
    const float* Wn = (const float*)d_in[2];
    const float* Wr = (const float*)d_in[3];
    const float* bconv = (const float*)d_in[4];
    const float* gamma = (const float*)d_in[5];
    const float* beta = (const float*)d_in[6];
    const float* Wh = (const float*)d_in[7];
    const float* bh = (const float*)d_in[8];

    int N = in_sizes[0] / C;
    int E = in_sizes[1] / 2;
    int L = in_sizes[2] / (C * C);
    int num_seed = out_size / 64;
    int nchunks = (N + 255) / 256;

    char* ws = (char*)d_ws;
    size_t off = 0;
    auto alloc = [&](size_t bytes) {
        void* p = ws + off;
        off = (off + bytes + 255) & ~(size_t)255;
        return p;
    };
    // ---- zero region (one memset: barrier counters + deg + needed) ----
    int* bar = (int*)alloc((size_t)64 * 64 * 4);  // up to 64 one-shot barriers, 256B apart
    int* deg = (int*)alloc((size_t)N * 4);
    int* needed = (int*)alloc((size_t)N * 4);
    size_t zero_span = off;
    // ---- rest ----
    int* row_start = (int*)alloc((size_t)(N + 1) * 4);
    int* cursor = (int*)alloc((size_t)N * 4);
    int* nodelist = (int*)alloc((size_t)N * 4);
    int* Mptr = (int*)alloc(4);
    int* bsumD = (int*)alloc((size_t)nchunks * 4);
    int* bsumN = (int*)alloc((size_t)nchunks * 4);
    int* esrc = (int*)alloc((size_t)E * 4);
    unsigned short* xb = (unsigned short*)alloc((size_t)N * C * 2);
    unsigned short* aggb = (unsigned short*)alloc((size_t)N * C * 2);
    unsigned short* xA = (unsigned short*)alloc((size_t)N * C * 2);
    unsigned short* xB = (unsigned short*)alloc((size_t)N * C * 2);
    unsigned short* Wnb = (unsigned short*)alloc((size_t)L * C * C * 2);
    unsigned short* Wrb = (unsigned short*)alloc((size_t)L * C * C * 2);
    unsigned short* Whb = (unsigned short*)alloc((size_t)64 * C * 2);

    const int* srcIdx = ei;
    const int* dstIdx = ei + E;

    int n4x = N * C / 4;
    int n4w = L * C * C / 4;
    int n4h = 64 * C / 4;
    int useFrontier = (L == 2) ? 1 : 0;

    hipMemsetAsync(ws, 0, zero_span, stream);
    mega_kernel<<<NB, 256, 0, stream>>>(
        x, srcIdx, dstIdx, Wn, Wr, bconv, gamma, beta, Wh, bh, (float*)d_out,
        N, E, L, num_seed, nchunks, useFrontier, n4x, n4w, n4h,
        bar, deg, needed, row_start, cursor, nodelist, Mptr, bsumD, bsumN, esrc,
        xb, aggb, xA, xB, Wnb, Wrb, Whb);
}

// Round 10
// 162.591 us; speedup vs baseline: 4.1452x; 2.5568x over previous
//
#include <hip/hip_runtime.h>

#define C 128

typedef __attribute__((ext_vector_type(8))) short short8;
typedef __attribute__((ext_vector_type(16))) float floatx16;

__device__ __forceinline__ unsigned short f2b(float f) {
    union { float f; unsigned u; } v; v.f = f;
    unsigned u = v.u + 0x7fffu + ((v.u >> 16) & 1u);  // RNE
    return (unsigned short)(u >> 16);
}
__device__ __forceinline__ void acc_pair(unsigned u, float& lo, float& hi) {
    union { unsigned u; float f; } a, b;
    a.u = u << 16;
    b.u = u & 0xffff0000u;
    lo += a.f;
    hi += b.f;
}

// ------- frontier mark: needed = seeds ∪ in-neighbors(seeds) -------
__global__ void mark_kernel(const int* __restrict__ src, const int* __restrict__ dst,
                            int* __restrict__ needed, int E, int num_seed) {
    int t = blockIdx.x * blockDim.x + threadIdx.x;
    if (t < num_seed) needed[t] = 1;
    if (t < E) {
        int d = dst[t];
        if (d < num_seed) needed[src[t]] = 1;
    }
}

// ------- fused: fp32->bf16 casts (x, Wn, Wr, Wh) + FILTERED degree histogram -------
// needed[] was fully written by the preceding mark dispatch -> no race; filtering cuts
// the far-atomic count from E=600K to ~E*frontier_frac (~154K), the R1-proven config.
__global__ void cast_count_kernel(const float* __restrict__ x, unsigned short* __restrict__ xb, int n4x,
                                  const float* __restrict__ Wn, unsigned short* __restrict__ Wnb,
                                  const float* __restrict__ Wr, unsigned short* __restrict__ Wrb, int n4w,
                                  const float* __restrict__ Wh, unsigned short* __restrict__ Whb, int n4h,
                                  const int* __restrict__ dst, int* __restrict__ deg, int E,
                                  const int* __restrict__ needed,
                                  int castBlocks) {
    if ((int)blockIdx.x < castBlocks) {
        int i = blockIdx.x * blockDim.x + threadIdx.x;
        const float* in;
        unsigned short* out;
        int idx;
        if (i < n4x) { in = x; out = xb; idx = i; }
        else if (i < n4x + n4w) { in = Wn; out = Wnb; idx = i - n4x; }
        else if (i < n4x + 2 * n4w) { in = Wr; out = Wrb; idx = i - n4x - n4w; }
        else if (i < n4x + 2 * n4w + n4h) { in = Wh; out = Whb; idx = i - n4x - 2 * n4w; }
        else return;
        float4 v = ((const float4*)in)[idx];
        ushort4 o;
        o.x = f2b(v.x); o.y = f2b(v.y); o.z = f2b(v.z); o.w = f2b(v.w);
        ((ushort4*)out)[idx] = o;
    } else {
        int e = (blockIdx.x - castBlocks) * blockDim.x + threadIdx.x;
        if (e < E) {
            int d = dst[e];
            if (!needed || needed[d]) atomicAdd(&deg[d], 1);
        }
    }
}

// ---------------- scan phase 1: per-256-chunk sums (deg AND needed) ----------------
__global__ void scan_partial2_kernel(const int* __restrict__ deg, const int* __restrict__ needed,
                                     int* __restrict__ bsumD, int* __restrict__ bsumN, int n) {
    __shared__ int smD[256];
    __shared__ int smN[256];
    int t = threadIdx.x;
    int i = blockIdx.x * 256 + t;
    smD[t] = (i < n) ? deg[i] : 0;
    smN[t] = (i < n) ? needed[i] : 0;
    __syncthreads();
#pragma unroll
    for (int off = 128; off > 0; off >>= 1) {
        if (t < off) { smD[t] += smD[t + off]; smN[t] += smN[t + off]; }
        __syncthreads();
    }
    if (t == 0) { bsumD[blockIdx.x] = smD[0]; bsumN[blockIdx.x] = smN[0]; }
}

// ---- scan phase 2 (merged): offsets + chunk scans + CSR row_start/cursor + nodelist/M ----
__global__ void scan_scatter2_kernel(const int* __restrict__ deg, const int* __restrict__ needed,
                                     const int* __restrict__ bsumD, const int* __restrict__ bsumN,
                                     int* __restrict__ row_start, int* __restrict__ cursor,
                                     int* __restrict__ nodelist, int* __restrict__ Mptr,
                                     int n) {
    __shared__ int osmD[256];
    __shared__ int osmN[256];
    __shared__ int smD[256];
    __shared__ int smN[256];
    int t = threadIdx.x, bid = blockIdx.x;
    int sD = 0, sN = 0;
    for (int i = t; i < bid; i += 256) { sD += bsumD[i]; sN += bsumN[i]; }
    osmD[t] = sD; osmN[t] = sN;
    __syncthreads();
#pragma unroll
    for (int off = 128; off > 0; off >>= 1) {
        if (t < off) { osmD[t] += osmD[t + off]; osmN[t] += osmN[t + off]; }
        __syncthreads();
    }
    int boffD = osmD[0], boffN = osmN[0];
    int i = bid * 256 + t;
    int d = (i < n) ? deg[i] : 0;
    int nd = (i < n) ? needed[i] : 0;
    smD[t] = d; smN[t] = nd;
    __syncthreads();
    for (int off = 1; off < 256; off <<= 1) {
        int vD = (t >= off) ? smD[t - off] : 0;
        int vN = (t >= off) ? smN[t - off] : 0;
        __syncthreads();
        smD[t] += vD; smN[t] += vN;
        __syncthreads();
    }
    int exD = smD[t] - d + boffD;
    int exN = smN[t] - nd + boffN;
    if (i < n) {
        row_start[i] = exD;
        cursor[i] = exD;
        if (nd) nodelist[exN] = i;
        if (i == n - 1) { row_start[n] = exD + d; *Mptr = exN + nd; }
    }
}

// ---------------- bucket edges by dst (counting sort, frontier-filtered) ----------------
__global__ void bucket_kernel(const int* __restrict__ src, const int* __restrict__ dst,
                              int* __restrict__ cursor, int* __restrict__ esrc, int E,
                              const int* __restrict__ needed) {
    int e = blockIdx.x * blockDim.x + threadIdx.x;
    if (e < E) {
        int d = dst[e];
        if (!needed || needed[d]) {
            int p = atomicAdd(&cursor[d], 1);
            esrc[p] = src[e];
        }
    }
}

// ------- mean aggregation: QUARTER-wave per node, 8-deep row ILP, high-TLP grid -------
// If nodelist != nullptr: list position -> original node id; output written COMPACT at
// list position. M read from Mptr; surplus waves exit immediately.
__global__ void aggregate_kernel(const unsigned short* __restrict__ xb, const int* __restrict__ row_start,
                                 const int* __restrict__ esrc,
                                 unsigned short* __restrict__ agg, int n,
                                 const int* __restrict__ nodelist, const int* __restrict__ Mptr) {
    int wid = (blockIdx.x * blockDim.x + threadIdx.x) >> 6;
    int lane = threadIdx.x & 63;
    int q = lane >> 4, l16 = lane & 15;
    int qb = lane & 48;
    int pos = wid * 4 + q;
    int m = Mptr ? *Mptr : n;
    if (pos >= m) return;
    int node = nodelist ? nodelist[pos] : pos;

    int beg = row_start[node];
    int end = row_start[node + 1];
    size_t choff = (size_t)l16 * 8;

    float a0 = 0.f, a1 = 0.f, a2 = 0.f, a3 = 0.f, a4 = 0.f, a5 = 0.f, a6 = 0.f, a7 = 0.f;

    for (int base = beg; base < end; base += 16) {
        int cnt = min(end - base, 16);
        int e_val = (base + l16 < end) ? esrc[base + l16] : 0;
        int j = 0;
        for (; j + 8 <= cnt; j += 8) {
            int s0 = __shfl(e_val, qb | j, 64);
            int s1 = __shfl(e_val, qb | (j + 1), 64);
            int s2 = __shfl(e_val, qb | (j + 2), 64);
            int s3 = __shfl(e_val, qb | (j + 3), 64);
            int s4 = __shfl(e_val, qb | (j + 4), 64);
            int s5 = __shfl(e_val, qb | (j + 5), 64);
            int s6 = __shfl(e_val, qb | (j + 6), 64);
            int s7 = __shfl(e_val, qb | (j + 7), 64);
            uint4 v0 = *(const uint4*)(xb + (size_t)s0 * C + choff);
            uint4 v1 = *(const uint4*)(xb + (size_t)s1 * C + choff);
            uint4 v2 = *(const uint4*)(xb + (size_t)s2 * C + choff);
            uint4 v3 = *(const uint4*)(xb + (size_t)s3 * C + choff);
            uint4 v4 = *(const uint4*)(xb + (size_t)s4 * C + choff);
            uint4 v5 = *(const uint4*)(xb + (size_t)s5 * C + choff);
            uint4 v6 = *(const uint4*)(xb + (size_t)s6 * C + choff);
            uint4 v7 = *(const uint4*)(xb + (size_t)s7 * C + choff);
            acc_pair(v0.x, a0, a1); acc_pair(v0.y, a2, a3); acc_pair(v0.z, a4, a5); acc_pair(v0.w, a6, a7);
            acc_pair(v1.x, a0, a1); acc_pair(v1.y, a2, a3); acc_pair(v1.z, a4, a5); acc_pair(v1.w, a6, a7);
            acc_pair(v2.x, a0, a1); acc_pair(v2.y, a2, a3); acc_pair(v2.z, a4, a5); acc_pair(v2.w, a6, a7);
            acc_pair(v3.x, a0, a1); acc_pair(v3.y, a2, a3); acc_pair(v3.z, a4, a5); acc_pair(v3.w, a6, a7);
            acc_pair(v4.x, a0, a1); acc_pair(v4.y, a2, a3); acc_pair(v4.z, a4, a5); acc_pair(v4.w, a6, a7);
            acc_pair(v5.x, a0, a1); acc_pair(v5.y, a2, a3); acc_pair(v5.z, a4, a5); acc_pair(v5.w, a6, a7);
            acc_pair(v6.x, a0, a1); acc_pair(v6.y, a2, a3); acc_pair(v6.z, a4, a5); acc_pair(v6.w, a6, a7);
            acc_pair(v7.x, a0, a1); acc_pair(v7.y, a2, a3); acc_pair(v7.z, a4, a5); acc_pair(v7.w, a6, a7);
        }
        for (; j + 4 <= cnt; j += 4) {
            int s0 = __shfl(e_val, qb | j, 64);
            int s1 = __shfl(e_val, qb | (j + 1), 64);
            int s2 = __shfl(e_val, qb | (j + 2), 64);
            int s3 = __shfl(e_val, qb | (j + 3), 64);
            uint4 v0 = *(const uint4*)(xb + (size_t)s0 * C + choff);
            uint4 v1 = *(const uint4*)(xb + (size_t)s1 * C + choff);
            uint4 v2 = *(const uint4*)(xb + (size_t)s2 * C + choff);
            uint4 v3 = *(const uint4*)(xb + (size_t)s3 * C + choff);
            acc_pair(v0.x, a0, a1); acc_pair(v0.y, a2, a3); acc_pair(v0.z, a4, a5); acc_pair(v0.w, a6, a7);
            acc_pair(v1.x, a0, a1); acc_pair(v1.y, a2, a3); acc_pair(v1.z, a4, a5); acc_pair(v1.w, a6, a7);
            acc_pair(v2.x, a0, a1); acc_pair(v2.y, a2, a3); acc_pair(v2.z, a4, a5); acc_pair(v2.w, a6, a7);
            acc_pair(v3.x, a0, a1); acc_pair(v3.y, a2, a3); acc_pair(v3.z, a4, a5); acc_pair(v3.w, a6, a7);
        }
        for (; j < cnt; ++j) {
            int s0 = __shfl(e_val, qb | j, 64);
            uint4 v0 = *(const uint4*)(xb + (size_t)s0 * C + choff);
            acc_pair(v0.x, a0, a1); acc_pair(v0.y, a2, a3); acc_pair(v0.z, a4, a5); acc_pair(v0.w, a6, a7);
        }
    }

    float sc = 1.0f / fmaxf((float)(end - beg), 1.0f);
    uint4 o;
    o.x = ((unsigned)f2b(a1 * sc) << 16) | (unsigned)f2b(a0 * sc);
    o.y = ((unsigned)f2b(a3 * sc) << 16) | (unsigned)f2b(a2 * sc);
    o.z = ((unsigned)f2b(a5 * sc) << 16) | (unsigned)f2b(a4 * sc);
    o.w = ((unsigned)f2b(a7 * sc) << 16) | (unsigned)f2b(a6 * sc);
    *(uint4*)(agg + (size_t)pos * C + choff) = o;
}

// ---- MFMA GEMM, 64-row blocks (h = agg@Wn^T + x@Wr^T + b) + LN + ReLU (+fused head) ----
// Block = 64 rows x 128 cols, 4 waves, one tile per block. If Whb != nullptr (final
// layer), post-LN activations stay in Xs and the block finishes act@Wh^T + bh -> out.
// Otherwise post-LN tile is staged in Xs and written to Xout with cooperative 16-B stores.
// If nodelist != nullptr: Aagg compact (row = list pos); Xin gathered / Xout scattered
// via nodelist; M read from Mptr (surplus blocks exit).
__launch_bounds__(256)
__global__ void gemm_mfma_ln_relu_kernel(const unsigned short* __restrict__ Aagg,
                                         const unsigned short* __restrict__ Xin,
                                         const unsigned short* __restrict__ Wn,
                                         const unsigned short* __restrict__ Wr,
                                         const float* __restrict__ bconv, const float* __restrict__ gamma,
                                         const float* __restrict__ beta, unsigned short* __restrict__ Xout,
                                         int n,
                                         const int* __restrict__ nodelist, const int* __restrict__ Mptr,
                                         const unsigned short* __restrict__ Whb,
                                         const float* __restrict__ bh, float* __restrict__ out) {
    __shared__ unsigned short Xs[64][136];
    __shared__ unsigned short Ws[128][136];
    __shared__ float Ls[64][2];
    __shared__ float Lss[64][2];

    int m = Mptr ? *Mptr : n;
    int row0 = blockIdx.x * 64;
    if (row0 >= m) return;

    int tid = threadIdx.x;
    int wave = tid >> 6, lane = tid & 63;
    int rh = wave & 1, ch = wave >> 1;
    int l31 = lane & 31, half = lane >> 5;

    floatx16 acc0, acc1;
#pragma unroll
    for (int i = 0; i < 16; ++i) { acc0[i] = 0.f; acc1[i] = 0.f; }

#pragma unroll
    for (int phase = 0; phase < 2; ++phase) {
        const unsigned short* Ap = phase ? Xin : Aagg;
        const unsigned short* Wp = phase ? Wr : Wn;
        __syncthreads();
#pragma unroll
        for (int i = 0; i < 4; ++i) {
            int cidx = tid + 256 * i;
            int r = cidx >> 4, koff = (cidx & 15) * 8;
            uint4 v = make_uint4(0u, 0u, 0u, 0u);
            int rg = row0 + r;
            if (rg < m) {
                int rowid = (phase && nodelist) ? nodelist[rg] : rg;
                v = *(const uint4*)(Ap + (size_t)rowid * C + koff);
            }
            *(uint4*)&Xs[r][koff] = v;
        }
#pragma unroll
        for (int i = 0; i < 8; ++i) {
            int cidx = tid + 256 * i;
            int r = cidx >> 4, koff = (cidx & 15) * 8;
            uint4 v = *(const uint4*)(Wp + (size_t)r * C + koff);
            *(uint4*)&Ws[r][koff] = v;
        }
        __syncthreads();
#pragma unroll
        for (int kc = 0; kc < C; kc += 16) {
            int ko = kc + half * 8;
            short8 a = *(const short8*)&Xs[rh * 32 + l31][ko];
            short8 b0 = *(const short8*)&Ws[ch * 64 + l31][ko];
            short8 b1 = *(const short8*)&Ws[ch * 64 + 32 + l31][ko];
            acc0 = __builtin_amdgcn_mfma_f32_32x32x16_bf16(a, b0, acc0, 0, 0, 0);
            acc1 = __builtin_amdgcn_mfma_f32_32x32x16_bf16(a, b1, acc1, 0, 0, 0);
        }
    }

    int col0 = ch * 64 + l31;
    int col1 = col0 + 32;
    float bc0 = bconv[col0], bc1 = bconv[col1];
#pragma unroll
    for (int r = 0; r < 16; ++r) {
        float h0 = acc0[r] + bc0;
        float h1 = acc1[r] + bc1;
        float s = h0 + h1, ss = h0 * h0 + h1 * h1;
#pragma unroll
        for (int mk = 1; mk < 32; mk <<= 1) {
            s += __shfl_xor(s, mk, 64);
            ss += __shfl_xor(ss, mk, 64);
        }
        if (l31 == 0) {
            int row_l = rh * 32 + (r & 3) + 8 * (r >> 2) + 4 * half;
            Ls[row_l][ch] = s;
            Lss[row_l][ch] = ss;
        }
    }
    __syncthreads();  // all MFMA done; Ls/Lss visible; Xs/Ws now safe to overwrite

    // final layer: stage Wh (64 x 128 bf16) into Ws (safe: phase-1 MFMA is done)
    if (Whb) {
#pragma unroll
        for (int i = 0; i < 4; ++i) {
            int cidx = tid + 256 * i;
            int r = cidx >> 4, koff = (cidx & 15) * 8;
            uint4 v = *(const uint4*)(Whb + (size_t)r * C + koff);
            *(uint4*)&Ws[r][koff] = v;
        }
    }

    float g0 = gamma[col0], g1 = gamma[col1];
    float be0 = beta[col0], be1 = beta[col1];
#pragma unroll
    for (int r = 0; r < 16; ++r) {
        int row_l = rh * 32 + (r & 3) + 8 * (r >> 2) + 4 * half;
        float s = Ls[row_l][0] + Ls[row_l][1];
        float ss = Lss[row_l][0] + Lss[row_l][1];
        float mu = s * (1.0f / 128.0f);
        float var = ss * (1.0f / 128.0f) - mu * mu;
        float rs = rsqrtf(var + 1e-5f);
        float h0 = acc0[r] + bc0;
        float h1 = acc1[r] + bc1;
        float o0 = fmaxf((h0 - mu) * rs * g0 + be0, 0.f);
        float o1 = fmaxf((h1 - mu) * rs * g1 + be1, 0.f);
        Xs[row_l][col0] = f2b(o0);
        Xs[row_l][col1] = f2b(o1);
    }
    __syncthreads();  // post-LN tile complete in Xs (and Wh in Ws if final)

    if (Whb) {
        floatx16 hc;
#pragma unroll
        for (int i = 0; i < 16; ++i) hc[i] = 0.f;
        int m0 = rh * 32, n0 = ch * 32;
#pragma unroll
        for (int kc = 0; kc < C; kc += 16) {
            int ko = kc + half * 8;
            short8 a = *(const short8*)&Xs[m0 + l31][ko];
            short8 b = *(const short8*)&Ws[n0 + l31][ko];
            hc = __builtin_amdgcn_mfma_f32_32x32x16_bf16(a, b, hc, 0, 0, 0);
        }
        int oc = n0 + l31;
        float bhv = bh[oc];
#pragma unroll
        for (int r = 0; r < 16; ++r) {
            int row_l = m0 + (r & 3) + 8 * (r >> 2) + 4 * half;
            int rg = row0 + row_l;
            if (rg < m) out[(size_t)rg * 64 + oc] = hc[r] + bhv;
        }
    } else {
        // cooperative vectorized writeback: 16 B per thread per iter
#pragma unroll
        for (int i = 0; i < 4; ++i) {
            int cidx = tid + 256 * i;
            int r = cidx >> 4, koff = (cidx & 15) * 8;
            int rg = row0 + r;
            if (rg < m) {
                int orow = nodelist ? nodelist[rg] : rg;
                *(uint4*)(Xout + (size_t)orow * C + koff) = *(const uint4*)&Xs[r][koff];
            }
        }
    }
}

extern "C" void kernel_launch(void* const* d_in, const int* in_sizes, int n_in,
                              void* d_out, int out_size, void* d_ws, size_t ws_size,
                              hipStream_t stream) {
    const float* x = (const float*)d_in[0];
    const int* ei = (const int*)d_in[1];
    const float* Wn = (const float*)d_in[2];
    const float* Wr = (const float*)d_in[3];
    const float* bconv = (const float*)d_in[4];
    const float* gamma = (const float*)d_in[5];
    const float* beta = (const float*)d_in[6];
    const float* Wh = (const float*)d_in[7];
    const float* bh = (const float*)d_in[8];

    int N = in_sizes[0] / C;
    int E = in_sizes[1] / 2;
    int L = in_sizes[2] / (C * C);
    int num_seed = out_size / 64;
    int nchunks = (N + 255) / 256;

    char* ws = (char*)d_ws;
    size_t off = 0;
    auto alloc = [&](size_t bytes) {
        void* p = ws + off;
        off = (off + bytes + 255) & ~(size_t)255;
        return p;
    };
    int* degneed = (int*)alloc((size_t)2 * N * 4);  // deg | needed, one memset
    int* deg = degneed;
    int* needed = degneed + N;
    int* row_start = (int*)alloc((size_t)(N + 1) * 4);
    int* cursor = (int*)alloc((size_t)N * 4);
    int* nodelist = (int*)alloc((size_t)N * 4);
    int* Mptr = (int*)alloc(4);
    int* bsumD = (int*)alloc((size_t)nchunks * 4);
    int* bsumN = (int*)alloc((size_t)nchunks * 4);
    int* esrc = (int*)alloc((size_t)E * 4);
    unsigned short* xb = (unsigned short*)alloc((size_t)N * C * 2);
    unsigned short* aggb = (unsigned short*)alloc((size_t)N * C * 2);
    unsigned short* xA = (unsigned short*)alloc((size_t)N * C * 2);
    unsigned short* xB = (unsigned short*)alloc((size_t)N * C * 2);
    unsigned short* Wnb = (unsigned short*)alloc((size_t)L * C * C * 2);
    unsigned short* Wrb = (unsigned short*)alloc((size_t)L * C * C * 2);
    unsigned short* Whb = (unsigned short*)alloc((size_t)64 * C * 2);

    const int* srcIdx = ei;
    const int* dstIdx = ei + E;

    int n4x = N * C / 4;
    int n4w = L * C * C / 4;
    int n4h = 64 * C / 4;
    int castBlocks = (n4x + 2 * n4w + n4h + 255) / 256;
    int degBlocks = (E + 255) / 256;

    // CSR filtering by frontier is only valid when layer 0 IS the frontier layer (L==2)
    const int* filt = (L == 2) ? needed : nullptr;

    hipMemsetAsync(degneed, 0, (size_t)2 * N * 4, stream);
    int markBlocks = (max(E, num_seed) + 255) / 256;
    mark_kernel<<<markBlocks, 256, 0, stream>>>(srcIdx, dstIdx, needed, E, num_seed);
    cast_count_kernel<<<castBlocks + degBlocks, 256, 0, stream>>>(
        x, xb, n4x, Wn, Wnb, Wr, Wrb, n4w, Wh, Whb, n4h, dstIdx, deg, E, filt, castBlocks);
    scan_partial2_kernel<<<nchunks, 256, 0, stream>>>(deg, needed, bsumD, bsumN, N);
    scan_scatter2_kernel<<<nchunks, 256, 0, stream>>>(deg, needed, bsumD, bsumN,
                                                      row_start, cursor, nodelist, Mptr, N);
    bucket_kernel<<<degBlocks, 256, 0, stream>>>(srcIdx, dstIdx, cursor, esrc, E, filt);

    const unsigned short* cur = xb;
    unsigned short* bufs[2] = {xA, xB};
    for (int l = 0; l < L; ++l) {
        bool last = (l == L - 1);
        bool front = !last && (l == L - 2);  // receptive-field (frontier) layer
        int nl = last ? num_seed : N;
        const int* list = front ? nodelist : nullptr;
        const int* Mp = front ? Mptr : nullptr;
        unsigned short* nxt = bufs[l & 1];
        int aggThreads = ((nl + 3) / 4) * 64;
        aggregate_kernel<<<(aggThreads + 255) / 256, 256, 0, stream>>>(
            cur, row_start, esrc, aggb, nl, list, Mp);
        gemm_mfma_ln_relu_kernel<<<(nl + 63) / 64, 256, 0, stream>>>(
            aggb, cur, Wnb + (size_t)l * C * C, Wrb + (size_t)l * C * C,
            bconv + (size_t)l * C, gamma + (size_t)l * C, beta + (size_t)l * C, nxt, nl,
            list, Mp,
            last ? Whb : (const unsigned short*)nullptr, bh, (float*)d_out);
        cur = nxt;
    }
}